// Round 15
// baseline (473.508 us; speedup 1.0000x reference)
//
#include <hip/hip_runtime.h>
#include <math.h>

#define N_ENTITY 200000
#define EMBED    64
#define N_EDGES  6400000
#define BATCH    1024
#define QLEN     20
#define NNEG     5
#define NSEL     (BATCH + BATCH + BATCH*NNEG)   // 7168 gathered rows
#define BM_WORDS ((N_ENTITY + 31) / 32)
#define COLMASK  0x3FFFF
#define VALMASK  0xFFFC0000u
#define FP8SCALE 256.0f
#define FP8INV   (1.0f/256.0f)

#define BROWS     512                                // rows per bucket
#define ROWSH     9
#define NBUCKET   ((N_ENTITY + BROWS - 1) / BROWS)   // 391
#define NBLK_PART 512
#define TPART     1024                               // threads/block for hist+scatter
#define SCAP      17000                              // LDS-staged edges per bucket

typedef unsigned int   uint32;
typedef unsigned short ushort16;
typedef unsigned char  uchar8;
typedef float v2f __attribute__((ext_vector_type(2)));

__device__ __forceinline__ ushort16 f2bf(float f) {
    uint32 b = __float_as_uint(f);
    uint32 r = (b + 0x7FFFu + ((b >> 16) & 1u)) >> 16;   // RNE
    return (ushort16)r;
}
__device__ __forceinline__ float pval(uint32 p) { return __uint_as_float(p & VALMASK); }
__device__ __forceinline__ v2f dec8(uint32 us) {
    return __builtin_amdgcn_cvt_pk_f32_fp8((int)us, false);
}

// ---------------------------------------------- sel helpers ---------------
__device__ __forceinline__ int sel_row(int i, const int* users, const int* items,
                                       const int* negs) {
    if (i < BATCH)        return users[i];
    if (i < 2 * BATCH)    return items[i - BATCH];
    return negs[i - 2 * BATCH];
}

// ------------------------------------------------------ edge partition ----
__global__ void part_hist_kernel(const int* __restrict__ erow,
                                 int* __restrict__ bucket_cnt,
                                 int* __restrict__ blockBase) {
    __shared__ int h[NBUCKET];
    int blk = blockIdx.x, t = threadIdx.x;
    for (int i = t; i < NBUCKET; i += TPART) h[i] = 0;
    __syncthreads();
    int per = (N_EDGES + NBLK_PART - 1) / NBLK_PART;
    int s = blk * per, e = min(s + per, N_EDGES);
    for (int j = s + t; j < e; j += TPART)
        atomicAdd(&h[erow[j] >> ROWSH], 1);
    __syncthreads();
    for (int i = t; i < NBUCKET; i += TPART)
        blockBase[blk * NBUCKET + i] = atomicAdd(&bucket_cnt[i], h[i]);
}

__global__ void bucket_scan_kernel(const int* __restrict__ cnt,
                                   int* __restrict__ bstart) {
    __shared__ int s[256];
    int t = threadIdx.x;
    int i0 = t * 2, i1 = t * 2 + 1;
    int c0 = (i0 < NBUCKET) ? cnt[i0] : 0;
    int c1 = (i1 < NBUCKET) ? cnt[i1] : 0;
    s[t] = c0 + c1; __syncthreads();
    for (int off = 1; off < 256; off <<= 1) {
        int x = (t >= off) ? s[t - off] : 0;
        __syncthreads();
        s[t] += x;
        __syncthreads();
    }
    int excl = t ? s[t - 1] : 0;
    if (i0 <= NBUCKET) { if (i0 < NBUCKET) bstart[i0] = excl; else bstart[NBUCKET] = excl; }
    excl += c0;
    if (i1 <= NBUCKET) { if (i1 < NBUCKET) bstart[i1] = excl; else bstart[NBUCKET] = excl; }
    if (t == 255) bstart[NBUCKET] = s[255];   // = N_EDGES
}

// scatter into bucket-grouped combined int2 stream (single stream, 8 B/edge)
__global__ void part_scatter_kernel(const int* __restrict__ erow,
                                    const int* __restrict__ ecol,
                                    const float* __restrict__ evalv,
                                    const int* __restrict__ bstart,
                                    const int* __restrict__ blockBase,
                                    int2* __restrict__ ebuf) {
    __shared__ int cur[NBUCKET];
    int blk = blockIdx.x, t = threadIdx.x;
    for (int i = t; i < NBUCKET; i += TPART)
        cur[i] = bstart[i] + blockBase[blk * NBUCKET + i];
    __syncthreads();
    int per = (N_EDGES + NBLK_PART - 1) / NBLK_PART;
    int s = blk * per, e = min(s + per, N_EDGES);
    int j = s + t;
    for (; j + TPART < e; j += 2 * TPART) {
        int   r0 = erow[j],       r1 = erow[j + TPART];
        int   c0 = ecol[j],       c1 = ecol[j + TPART];
        float v0 = evalv[j],      v1 = evalv[j + TPART];
        int p0 = atomicAdd(&cur[r0 >> ROWSH], 1);
        int p1 = atomicAdd(&cur[r1 >> ROWSH], 1);
        ebuf[p0] = make_int2(c0 | ((r0 & (BROWS-1)) << 18), (int)f2bf(v0));
        ebuf[p1] = make_int2(c1 | ((r1 & (BROWS-1)) << 18), (int)f2bf(v1));
    }
    for (; j < e; j += TPART) {
        int   r = erow[j];
        int   c = ecol[j];
        float v = evalv[j];
        int pos = atomicAdd(&cur[r >> ROWSH], 1);
        ebuf[pos] = make_int2(c | ((r & (BROWS-1)) << 18), (int)f2bf(v));
    }
}

// ------- bucket-local counting sort -> exact CSR, LDS-staged single read --
__global__ void bucket_sort_kernel(const int2* __restrict__ ebuf,
                                   const int* __restrict__ bstart,
                                   int* __restrict__ epack,
                                   int* __restrict__ rowptr) {
    __shared__ int  cur[BROWS];
    __shared__ int2 sbuf[SCAP];    // 136 KB: whole bucket staged once
    int b = blockIdx.x, t = threadIdx.x;   // t in [0,512)
    int beg = bstart[b], end = bstart[b + 1];
    int cnt  = end - beg;
    int scnt = min(cnt, SCAP);
    cur[t] = 0;
    __syncthreads();
    // pass 1: load + histogram (staged portion lands in LDS)
    for (int j = t; j < scnt; j += BROWS) {
        int2 e = ebuf[beg + j];
        sbuf[j] = e;
        atomicAdd(&cur[((unsigned)e.x) >> 18], 1);
    }
    for (int j = scnt + t; j < cnt; j += BROWS)    // spill (statistically never)
        atomicAdd(&cur[((unsigned)ebuf[beg + j].x) >> 18], 1);
    __syncthreads();
    int own = cur[t];
    __syncthreads();
    cur[t] = own;
    __syncthreads();
    for (int off = 1; off < BROWS; off <<= 1) {
        int x = (t >= off) ? cur[t - off] : 0;
        __syncthreads();
        cur[t] += x;
        __syncthreads();
    }
    int excl = cur[t] - own;
    __syncthreads();
    int r = (b << ROWSH) + t;
    if (r <= N_ENTITY) rowptr[r] = beg + excl;
    cur[t] = beg + excl;
    __syncthreads();
    // pass 2: scatter from LDS
    for (int j = t; j < scnt; j += BROWS) {
        int2 e = sbuf[j];
        int pos = atomicAdd(&cur[((unsigned)e.x) >> 18], 1);   // LDS atomic
        epack[pos] = (e.x & COLMASK) | ((e.y & 0xFFFC) << 16);
    }
    for (int j = scnt + t; j < cnt; j += BROWS) {  // spill path
        int2 e = ebuf[beg + j];
        int pos = atomicAdd(&cur[((unsigned)e.x) >> 18], 1);
        epack[pos] = (e.x & COLMASK) | ((e.y & 0xFFFC) << 16);
    }
}

// ---------------------- needed-rows bitmap (sel rows + their neighbors) ---
__global__ void need_build_kernel(const int* __restrict__ users,
                                  const int* __restrict__ items,
                                  const int* __restrict__ negs,
                                  const int* __restrict__ rowptr,
                                  const int* __restrict__ epack,
                                  unsigned int* __restrict__ bm) {
    int lane = threadIdx.x & 63;
    int wave = blockIdx.x * (blockDim.x >> 6) + (threadIdx.x >> 6);
    if (wave >= NSEL) return;
    int idx = sel_row(wave, users, items, negs);
    if (lane == 0) atomicOr(&bm[idx >> 5], 1u << (idx & 31));
    int beg = rowptr[idx], end = rowptr[idx + 1];
    for (int j = beg + lane; j < end; j += 64) {
        int c = epack[j] & COLMASK;
        atomicOr(&bm[c >> 5], 1u << (c & 31));
    }
}

// ------------------------- expand bmNeed into an (unordered) row list -----
__global__ void list_build_kernel(const unsigned int* __restrict__ bm,
                                  int* __restrict__ rowlist,
                                  int* __restrict__ nrow) {
    int w = blockIdx.x * blockDim.x + threadIdx.x;
    if (w >= BM_WORDS) return;
    unsigned int m = bm[w];
    if (!m) return;
    int n = __popc(m);
    int base = atomicAdd(nrow, n);
    while (m) {
        int b = __ffs(m) - 1;
        m &= m - 1;
        rowlist[base++] = (w << 5) + b;
    }
}

// ------------------------------------ entity -> fp8 (scaled x256) --------
__global__ void conv_fp8_kernel(const float* __restrict__ src,
                                uchar8* __restrict__ dst) {
    int i = (blockIdx.x * blockDim.x + threadIdx.x) * 8;
    if (i >= N_ENTITY * EMBED) return;
    float4 v0 = *(const float4*)&src[i];
    float4 v1 = *(const float4*)&src[i + 4];
    int w0 = __builtin_amdgcn_cvt_pk_fp8_f32(v0.x * FP8SCALE, v0.y * FP8SCALE, 0, false);
    w0     = __builtin_amdgcn_cvt_pk_fp8_f32(v0.z * FP8SCALE, v0.w * FP8SCALE, w0, true);
    int w1 = __builtin_amdgcn_cvt_pk_fp8_f32(v1.x * FP8SCALE, v1.y * FP8SCALE, 0, false);
    w1     = __builtin_amdgcn_cvt_pk_fp8_f32(v1.z * FP8SCALE, v1.w * FP8SCALE, w1, true);
    *(uint2*)&dst[i] = make_uint2((uint32)w0, (uint32)w1);
}

// ------------------------------- half-wave fp8 CSR SpMM (packed edges) ----
template<int USELIST>
__global__ void spmm_h_kernel(const uchar8* __restrict__ src,
                              uchar8* __restrict__ dst,
                              const int* __restrict__ rowptr,
                              const int* __restrict__ epack,
                              const int* __restrict__ rowlist,
                              const int* __restrict__ nrowp) {
    int lane = threadIdx.x & 63;
    int half = lane >> 5;
    int l2   = lane & 31;
    int wave  = blockIdx.x * (blockDim.x >> 6) + (threadIdx.x >> 6);
    int nwave = gridDim.x * (blockDim.x >> 6);
    int nrow = USELIST ? *nrowp : N_ENTITY;
    for (int it = wave; it < nrow; it += nwave) {
        int row = USELIST ? rowlist[it] : it;
        int beg = rowptr[row], end = rowptr[row + 1];
        int cnt = end - beg;
        int h0  = cnt - (cnt >> 1);               // ceil half for half 0
        int s   = beg + half * h0;
        int e   = half ? end : (beg + h0);
        float ax = 0.f, ay = 0.f;
        int j = s;
        for (; j + 7 < e; j += 8) {
            int4 ca = *(const int4*)&epack[j];
            int4 cb = *(const int4*)&epack[j + 4];
            ushort16 u0 = *(const ushort16*)(src + (size_t)(ca.x & COLMASK) * EMBED + l2 * 2);
            ushort16 u1 = *(const ushort16*)(src + (size_t)(ca.y & COLMASK) * EMBED + l2 * 2);
            ushort16 u2 = *(const ushort16*)(src + (size_t)(ca.z & COLMASK) * EMBED + l2 * 2);
            ushort16 u3 = *(const ushort16*)(src + (size_t)(ca.w & COLMASK) * EMBED + l2 * 2);
            ushort16 u4 = *(const ushort16*)(src + (size_t)(cb.x & COLMASK) * EMBED + l2 * 2);
            ushort16 u5 = *(const ushort16*)(src + (size_t)(cb.y & COLMASK) * EMBED + l2 * 2);
            ushort16 u6 = *(const ushort16*)(src + (size_t)(cb.z & COLMASK) * EMBED + l2 * 2);
            ushort16 u7 = *(const ushort16*)(src + (size_t)(cb.w & COLMASK) * EMBED + l2 * 2);
            float v0 = pval(ca.x), v1 = pval(ca.y), v2 = pval(ca.z), v3 = pval(ca.w);
            float v4 = pval(cb.x), v5 = pval(cb.y), v6 = pval(cb.z), v7 = pval(cb.w);
            v2f x0 = dec8(u0), x1 = dec8(u1), x2 = dec8(u2), x3 = dec8(u3);
            v2f x4 = dec8(u4), x5 = dec8(u5), x6 = dec8(u6), x7 = dec8(u7);
            ax += v0 * x0.x;  ay += v0 * x0.y;
            ax += v1 * x1.x;  ay += v1 * x1.y;
            ax += v2 * x2.x;  ay += v2 * x2.y;
            ax += v3 * x3.x;  ay += v3 * x3.y;
            ax += v4 * x4.x;  ay += v4 * x4.y;
            ax += v5 * x5.x;  ay += v5 * x5.y;
            ax += v6 * x6.x;  ay += v6 * x6.y;
            ax += v7 * x7.x;  ay += v7 * x7.y;
        }
        for (; j + 3 < e; j += 4) {
            int4 ca = *(const int4*)&epack[j];
            ushort16 u0 = *(const ushort16*)(src + (size_t)(ca.x & COLMASK) * EMBED + l2 * 2);
            ushort16 u1 = *(const ushort16*)(src + (size_t)(ca.y & COLMASK) * EMBED + l2 * 2);
            ushort16 u2 = *(const ushort16*)(src + (size_t)(ca.z & COLMASK) * EMBED + l2 * 2);
            ushort16 u3 = *(const ushort16*)(src + (size_t)(ca.w & COLMASK) * EMBED + l2 * 2);
            float v0 = pval(ca.x), v1 = pval(ca.y), v2 = pval(ca.z), v3 = pval(ca.w);
            v2f x0 = dec8(u0), x1 = dec8(u1), x2 = dec8(u2), x3 = dec8(u3);
            ax += v0 * x0.x;  ay += v0 * x0.y;
            ax += v1 * x1.x;  ay += v1 * x1.y;
            ax += v2 * x2.x;  ay += v2 * x2.y;
            ax += v3 * x3.x;  ay += v3 * x3.y;
        }
        for (; j < e; ++j) {
            uint32 pe = (uint32)epack[j];
            ushort16 u = *(const ushort16*)(src + (size_t)(pe & COLMASK) * EMBED + l2 * 2);
            float v = pval(pe);
            v2f x = dec8(u);
            ax += v * x.x;
            ay += v * x.y;
        }
        ax += __shfl_xor(ax, 32);
        ay += __shfl_xor(ay, 32);
        if (half == 0) {
            int pk = __builtin_amdgcn_cvt_pk_fp8_f32(ax, ay, 0, false);
            *(ushort16*)(dst + (size_t)row * EMBED + l2 * 2) = (ushort16)pk;
        }
    }
}

// layer-3 direct pull: sel[i] += (1/S) * sum_j val * h2[col]   (h2 fp8 xS)
__global__ void sel_pull_kernel(const uchar8* __restrict__ h,
                                const int* __restrict__ users,
                                const int* __restrict__ items,
                                const int* __restrict__ negs,
                                const int* __restrict__ rowptr,
                                const int* __restrict__ epack,
                                float* __restrict__ sel) {
    int lane = threadIdx.x & 63;
    int half = lane >> 5;
    int l2   = lane & 31;
    int wave = blockIdx.x * (blockDim.x >> 6) + (threadIdx.x >> 6);
    if (wave >= NSEL) return;
    int idx = sel_row(wave, users, items, negs);
    int beg = rowptr[idx], end = rowptr[idx + 1];
    int cnt = end - beg;
    int h0  = cnt - (cnt >> 1);
    int s   = beg + half * h0;
    int e   = half ? end : (beg + h0);
    float ax = 0.f, ay = 0.f;
    int j = s;
    for (; j + 7 < e; j += 8) {
        int4 ca = *(const int4*)&epack[j];
        int4 cb = *(const int4*)&epack[j + 4];
        ushort16 u0 = *(const ushort16*)(h + (size_t)(ca.x & COLMASK) * EMBED + l2 * 2);
        ushort16 u1 = *(const ushort16*)(h + (size_t)(ca.y & COLMASK) * EMBED + l2 * 2);
        ushort16 u2 = *(const ushort16*)(h + (size_t)(ca.z & COLMASK) * EMBED + l2 * 2);
        ushort16 u3 = *(const ushort16*)(h + (size_t)(ca.w & COLMASK) * EMBED + l2 * 2);
        ushort16 u4 = *(const ushort16*)(h + (size_t)(cb.x & COLMASK) * EMBED + l2 * 2);
        ushort16 u5 = *(const ushort16*)(h + (size_t)(cb.y & COLMASK) * EMBED + l2 * 2);
        ushort16 u6 = *(const ushort16*)(h + (size_t)(cb.z & COLMASK) * EMBED + l2 * 2);
        ushort16 u7 = *(const ushort16*)(h + (size_t)(cb.w & COLMASK) * EMBED + l2 * 2);
        float v0 = pval(ca.x), v1 = pval(ca.y), v2 = pval(ca.z), v3 = pval(ca.w);
        float v4 = pval(cb.x), v5 = pval(cb.y), v6 = pval(cb.z), v7 = pval(cb.w);
        v2f x0 = dec8(u0), x1 = dec8(u1), x2 = dec8(u2), x3 = dec8(u3);
        v2f x4 = dec8(u4), x5 = dec8(u5), x6 = dec8(u6), x7 = dec8(u7);
        ax += v0 * x0.x;  ay += v0 * x0.y;
        ax += v1 * x1.x;  ay += v1 * x1.y;
        ax += v2 * x2.x;  ay += v2 * x2.y;
        ax += v3 * x3.x;  ay += v3 * x3.y;
        ax += v4 * x4.x;  ay += v4 * x4.y;
        ax += v5 * x5.x;  ay += v5 * x5.y;
        ax += v6 * x6.x;  ay += v6 * x6.y;
        ax += v7 * x7.x;  ay += v7 * x7.y;
    }
    for (; j < e; ++j) {
        uint32 pe = (uint32)epack[j];
        ushort16 u = *(const ushort16*)(h + (size_t)(pe & COLMASK) * EMBED + l2 * 2);
        float v = pval(pe);
        v2f x = dec8(u);
        ax += v * x.x;
        ay += v * x.y;
    }
    ax += __shfl_xor(ax, 32);
    ay += __shfl_xor(ay, 32);
    if (half == 0) {
        sel[(size_t)wave * EMBED + l2 * 2]     += ax * FP8INV;
        sel[(size_t)wave * EMBED + l2 * 2 + 1] += ay * FP8INV;
    }
}

// ------------------------------------------------- sel accumulate ---------
__global__ void sel_init_kernel(const float* __restrict__ h,
                                const int* __restrict__ users,
                                const int* __restrict__ items,
                                const int* __restrict__ negs,
                                float* __restrict__ sel) {
    int tid = blockIdx.x * blockDim.x + threadIdx.x;
    if (tid >= NSEL * EMBED) return;
    int i = tid >> 6, d = tid & 63;
    int idx = sel_row(i, users, items, negs);
    sel[tid] = h[(size_t)idx * EMBED + d];
}

__global__ void sel_add_fp8_kernel(const uchar8* __restrict__ h,
                                   const int* __restrict__ users,
                                   const int* __restrict__ items,
                                   const int* __restrict__ negs,
                                   float* __restrict__ sel) {
    int tid = blockIdx.x * blockDim.x + threadIdx.x;
    if (tid >= NSEL * 32) return;
    int i = tid >> 5, d2 = tid & 31;
    int idx = sel_row(i, users, items, negs);
    ushort16 u = *(const ushort16*)(h + (size_t)idx * EMBED + d2 * 2);
    v2f x = dec8(u);
    sel[(size_t)i * EMBED + d2 * 2]     += x.x * FP8INV;
    sel[(size_t)i * EMBED + d2 * 2 + 1] += x.y * FP8INV;
}

// ------------------------------------ sentence encode: qkv projection -----
__global__ void qkv_kernel(const int* __restrict__ qwords,
                           const float* __restrict__ word_w,
                           const float* __restrict__ Win,
                           const float* __restrict__ bin,
                           float* __restrict__ qkv_g) {
    __shared__ float Wl[192][65];
    __shared__ float xw[QLEN][65];
    __shared__ float bl[192];
    int b = blockIdx.x, t = threadIdx.x;   // 256 threads

    for (int j = t; j < 192 * EMBED; j += 256) {
        int o = j >> 6, d = j & 63;
        Wl[o][d] = Win[j];
    }
    for (int j = t; j < 192; j += 256) bl[j] = bin[j];
    for (int j = t; j < QLEN * EMBED; j += 256) {
        int q = j >> 6, d = j & 63;
        int w = qwords[b * QLEN + q];
        xw[q][d] = word_w[(size_t)w * EMBED + d];
    }
    __syncthreads();

    for (int j = t; j < QLEN * 192; j += 256) {
        int q = j / 192, o = j % 192;
        float acc = bl[o];
        #pragma unroll
        for (int d = 0; d < EMBED; ++d) acc += xw[q][d] * Wl[o][d];
        qkv_g[(size_t)b * QLEN * 192 + j] = acc;
    }
}

// ------------------------------------- sentence encode: attention + out ---
__global__ void attn_kernel(const float* __restrict__ qkv_g,
                            const float* __restrict__ Wout,
                            const float* __restrict__ bout,
                            float* __restrict__ qenc) {
    __shared__ float qs[QLEN][195];
    __shared__ float ctx[QLEN][68];
    __shared__ float Wl[64][65];
    __shared__ float mctx[EMBED];
    int b = blockIdx.x, t = threadIdx.x;   // 128 threads

    for (int j = t; j < QLEN * 192; j += 128) {
        int q = j / 192, o = j % 192;
        qs[q][o] = qkv_g[(size_t)b * QLEN * 192 + j];
    }
    for (int j = t; j < EMBED * EMBED; j += 128) {
        int o = j >> 6, d = j & 63;
        Wl[o][d] = Wout[j];
    }
    __syncthreads();

    if (t < 4 * QLEN) {
        int h = t / QLEN, i = t % QLEN;
        float sc[QLEN];
        float mx = -1e30f;
        #pragma unroll
        for (int k = 0; k < QLEN; ++k) {
            float s = 0.f;
            #pragma unroll
            for (int d = 0; d < 16; ++d)
                s += qs[i][h*16 + d] * qs[k][EMBED + h*16 + d];
            s *= 0.25f;
            sc[k] = s;
            mx = fmaxf(mx, s);
        }
        float denom = 0.f;
        #pragma unroll
        for (int k = 0; k < QLEN; ++k) { sc[k] = expf(sc[k] - mx); denom += sc[k]; }
        float inv = 1.0f / denom;
        #pragma unroll
        for (int d = 0; d < 16; ++d) {
            float acc = 0.f;
            #pragma unroll
            for (int k = 0; k < QLEN; ++k)
                acc += sc[k] * qs[k][2*EMBED + h*16 + d];
            ctx[i][h*16 + d] = acc * inv;
        }
    }
    __syncthreads();

    if (t < EMBED) {
        float acc = 0.f;
        #pragma unroll
        for (int q = 0; q < QLEN; ++q) acc += ctx[q][t];
        mctx[t] = acc * (1.0f / QLEN);
    }
    __syncthreads();

    if (t < EMBED) {
        float acc = bout[t];
        #pragma unroll
        for (int d = 0; d < EMBED; ++d) acc += mctx[d] * Wl[t][d];
        qenc[b * EMBED + t] = acc;
    }
}

// --------------------------------------- fallback (atomic) path -----------
__global__ void spmm_kernel(const float* __restrict__ src, float* __restrict__ dst,
                            const int* __restrict__ erow, const int* __restrict__ ecol,
                            const float* __restrict__ evalv, int n_edges) {
    int lane  = threadIdx.x & 63;
    int wave  = blockIdx.x * (blockDim.x >> 6) + (threadIdx.x >> 6);
    int nwave = gridDim.x * (blockDim.x >> 6);
    for (int e = wave; e < n_edges; e += nwave) {
        int   r = erow[e];
        int   c = ecol[e];
        float v = evalv[e];
        float x = src[(size_t)c * EMBED + lane];
        atomicAdd(&dst[(size_t)r * EMBED + lane], v * x);
    }
}

__global__ void spmm_filtered_kernel(const float* __restrict__ src, float* __restrict__ dst,
                                     const int* __restrict__ erow, const int* __restrict__ ecol,
                                     const float* __restrict__ evalv,
                                     const unsigned int* __restrict__ bm, int n_edges) {
    int lane  = threadIdx.x & 63;
    int wave  = blockIdx.x * (blockDim.x >> 6) + (threadIdx.x >> 6);
    int nwave = gridDim.x * (blockDim.x >> 6);
    for (int e = wave; e < n_edges; e += nwave) {
        int r = erow[e];
        if (!((bm[r >> 5] >> (r & 31)) & 1u)) continue;
        int   c = ecol[e];
        float v = evalv[e];
        float x = src[(size_t)c * EMBED + lane];
        atomicAdd(&dst[(size_t)r * EMBED + lane], v * x);
    }
}

__global__ void bitmap_build_kernel(const int* __restrict__ users,
                                    const int* __restrict__ items,
                                    const int* __restrict__ negs,
                                    unsigned int* __restrict__ bm) {
    int i = blockIdx.x * blockDim.x + threadIdx.x;
    if (i >= NSEL) return;
    int idx = sel_row(i, users, items, negs);
    atomicOr(&bm[idx >> 5], 1u << (idx & 31));
}

__global__ void sel_accum_kernel(const float* __restrict__ h,
                                 const int* __restrict__ users,
                                 const int* __restrict__ items,
                                 const int* __restrict__ negs,
                                 float* __restrict__ sel, int init) {
    int tid = blockIdx.x * blockDim.x + threadIdx.x;
    if (tid >= NSEL * EMBED) return;
    int i = tid >> 6, d = tid & 63;
    int idx = sel_row(i, users, items, negs);
    float v = h[(size_t)idx * EMBED + d];
    if (init) sel[tid] = v;
    else      sel[tid] += v;
}

__global__ void sent_kernel(const int* __restrict__ qwords,
                            const float* __restrict__ word_w,
                            const float* __restrict__ Win,  const float* __restrict__ bin,
                            const float* __restrict__ Wout, const float* __restrict__ bout,
                            float* __restrict__ qenc) {
    __shared__ float x[QLEN][EMBED];
    __shared__ float qkv[QLEN][3*EMBED];
    __shared__ float ctx[QLEN][EMBED];
    __shared__ float mctx[EMBED];
    int b = blockIdx.x;
    int t = threadIdx.x;   // 0..127

    for (int j = t; j < QLEN*EMBED; j += 128) {
        int q = j >> 6, d = j & 63;
        int w = qwords[b*QLEN + q];
        x[q][d] = word_w[(size_t)w * EMBED + d];
    }
    __syncthreads();
    for (int j = t; j < QLEN*192; j += 128) {
        int q = j / 192, o = j % 192;
        float acc = bin[o];
        const float* wrow = &Win[o*EMBED];
        #pragma unroll
        for (int d = 0; d < EMBED; ++d) acc += x[q][d] * wrow[d];
        qkv[q][o] = acc;
    }
    __syncthreads();
    if (t < 4*QLEN) {
        int h = t / QLEN, i = t % QLEN;
        float sc[QLEN];
        float mx = -1e30f;
        #pragma unroll
        for (int k = 0; k < QLEN; ++k) {
            float s = 0.f;
            #pragma unroll
            for (int d = 0; d < 16; ++d)
                s += qkv[i][h*16 + d] * qkv[k][EMBED + h*16 + d];
            s *= 0.25f;
            sc[k] = s;
            mx = fmaxf(mx, s);
        }
        float denom = 0.f;
        #pragma unroll
        for (int k = 0; k < QLEN; ++k) { sc[k] = expf(sc[k] - mx); denom += sc[k]; }
        float inv = 1.0f / denom;
        #pragma unroll
        for (int d = 0; d < 16; ++d) {
            float acc = 0.f;
            #pragma unroll
            for (int k = 0; k < QLEN; ++k)
                acc += sc[k] * qkv[k][2*EMBED + h*16 + d];
            ctx[i][h*16 + d] = acc * inv;
        }
    }
    __syncthreads();
    if (t < EMBED) {
        float acc = 0.f;
        #pragma unroll
        for (int q = 0; q < QLEN; ++q) acc += ctx[q][t];
        mctx[t] = acc * (1.0f/QLEN);
    }
    __syncthreads();
    if (t < EMBED) {
        float acc = bout[t];
        const float* wrow = &Wout[t*EMBED];
        #pragma unroll
        for (int d = 0; d < EMBED; ++d) acc += mctx[d] * wrow[d];
        qenc[b*EMBED + t] = acc;
    }
}

// ----------------------------------------------------------------- losses --
__device__ __forceinline__ float log_sigmoid(float x) {
    float l = log1pf(expf(-fabsf(x)));
    return x >= 0.f ? -l : x - l;
}
__device__ __forceinline__ float wred(float v) {
    #pragma unroll
    for (int off = 32; off; off >>= 1) v += __shfl_xor(v, off);
    return v;
}

__global__ void loss_kernel(const float* __restrict__ sel,
                            const float* __restrict__ qenc,
                            float* __restrict__ out) {
    int b = blockIdx.x;
    int d = threadIdx.x;   // 0..63
    const float scale = 0.25f;
    float u   = sel[(size_t)b*EMBED + d] * scale;
    float pos = sel[(size_t)(BATCH + b)*EMBED + d] * scale;
    float p   = qenc[b*EMBED + d] + 0.1f * u;

    float s_up = wred(u * pos);
    float s_pp = wred(p * pos);
    float nu[NNEG], np_[NNEG];
    #pragma unroll
    for (int n = 0; n < NNEG; ++n) {
        float ng = sel[(size_t)(2*BATCH + b*NNEG + n)*EMBED + d] * scale;
        nu[n]  = wred(u * ng);
        np_[n] = wred(p * ng);
    }
    if (d == 0) {
        float cf = 0.f, srch_neg = 0.f;
        #pragma unroll
        for (int n = 0; n < NNEG; ++n) {
            cf       += -log_sigmoid(s_up - nu[n]);
            srch_neg += -log_sigmoid(-np_[n]);
        }
        float res = cf * (1.0f/(BATCH*NNEG))
                  + (-log_sigmoid(s_pp)) * (1.0f/BATCH)
                  + srch_neg * (1.0f/(BATCH*NNEG));
        atomicAdd(out, res);
    }
}

// ---------------------------------------------------------------- launch ---
extern "C" void kernel_launch(void* const* d_in, const int* in_sizes, int n_in,
                              void* d_out, int out_size, void* d_ws, size_t ws_size,
                              hipStream_t stream) {
    const float* entity_w   = (const float*)d_in[0];
    const float* word_w     = (const float*)d_in[1];
    const float* in_proj_w  = (const float*)d_in[2];
    const float* in_proj_b  = (const float*)d_in[3];
    const float* out_proj_w = (const float*)d_in[4];
    const float* out_proj_b = (const float*)d_in[5];
    const float* edge_val   = (const float*)d_in[6];
    const int*   users      = (const int*)d_in[7];
    const int*   items      = (const int*)d_in[8];
    const int*   qwords     = (const int*)d_in[9];
    const int*   neg_items  = (const int*)d_in[10];
    const int*   edge_row   = (const int*)d_in[11];
    const int*   edge_col   = (const int*)d_in[12];
    float* out = (float*)d_out;

    const size_t HN  = (size_t)N_ENTITY * EMBED;       // 12.8M elems
    const size_t HN8 = HN;                             // fp8 bytes (12.8 MB)
    const size_t EB  = sizeof(int2) * (size_t)N_EDGES; // 51.2 MB
    const size_t QKVN = (size_t)BATCH * QLEN * 192;

    size_t need = sizeof(int) * (size_t)N_EDGES        // epack
                + EB                                   // region A (ebuf -> e8,h1,h2)
                + sizeof(float) * (size_t)NSEL * EMBED // sel
                + sizeof(float) * (size_t)BATCH * EMBED// qenc
                + sizeof(int) * (size_t)(N_ENTITY + 1) // rowptr
                + sizeof(unsigned int) * (size_t)BM_WORDS
                + sizeof(float) * QKVN                 // qkv_g (build scratch overlays)
                + sizeof(int) * (size_t)N_ENTITY       // rowlist
                + 64;                                  // nrow + slack

    hipMemsetAsync(out, 0, sizeof(float) * out_size, stream);

    if (ws_size >= need) {
        char* base = (char*)d_ws;
        int*       epack = (int*)base;
        int2*      ebuf  = (int2*)(base + sizeof(int) * (size_t)N_EDGES);  // region A
        uchar8*    e8    = (uchar8*)ebuf;                                  // alias post-sort
        uchar8*    h1    = (uchar8*)ebuf + HN8;                            // alias post-sort
        uchar8*    h2    = (uchar8*)ebuf + 2 * HN8;                        // alias post-sort
        char* p = (char*)ebuf + EB;
        float*     sel   = (float*)p;        p += sizeof(float) * (size_t)NSEL * EMBED;
        float*     qenc  = (float*)p;        p += sizeof(float) * (size_t)BATCH * EMBED;
        int*       rowptr = (int*)p;         p += sizeof(int) * (size_t)(N_ENTITY + 1);
        unsigned int* bmNeed = (unsigned int*)p;  p += sizeof(unsigned int) * (size_t)BM_WORDS;
        float*     qkv_g = (float*)p;        p += sizeof(float) * QKVN;
        int*       rowlist = (int*)p;        p += sizeof(int) * (size_t)N_ENTITY;
        int*       nrow = (int*)p;
        // build scratch overlaid on qkv_g (dead until qkv_kernel, post-sort)
        int* bucket_cnt = (int*)qkv_g;
        int* bstart     = bucket_cnt + NBUCKET;
        int* blockBase  = bstart + NBUCKET + 1;   // ~0.8 MB << 15.7 MB

        hipMemsetAsync(bucket_cnt, 0, sizeof(int) * NBUCKET, stream);
        hipMemsetAsync(bmNeed, 0, sizeof(unsigned int) * BM_WORDS, stream);
        hipMemsetAsync(nrow, 0, sizeof(int), stream);

        // --- atomic-free CSR build -> packed 4B edges ---
        part_hist_kernel<<<NBLK_PART, TPART, 0, stream>>>(edge_row, bucket_cnt, blockBase);
        bucket_scan_kernel<<<1, 256, 0, stream>>>(bucket_cnt, bstart);
        part_scatter_kernel<<<NBLK_PART, TPART, 0, stream>>>(
            edge_row, edge_col, edge_val, bstart, blockBase, ebuf);
        bucket_sort_kernel<<<NBUCKET, BROWS, 0, stream>>>(ebuf, bstart, epack, rowptr);

        need_build_kernel<<<(NSEL + 3) / 4, 256, 0, stream>>>(
            users, items, neg_items, rowptr, epack, bmNeed);
        list_build_kernel<<<(BM_WORDS + 255) / 256, 256, 0, stream>>>(
            bmNeed, rowlist, nrow);

        // sentence encoder (qkv_g overlays dead build scratch)
        qkv_kernel<<<BATCH, 256, 0, stream>>>(qwords, word_w, in_proj_w, in_proj_b, qkv_g);
        attn_kernel<<<BATCH, 128, 0, stream>>>(qkv_g, out_proj_w, out_proj_b, qenc);

        // entity -> fp8 x256 (overwrites dead ebuf region)
        conv_fp8_kernel<<<(int)((HN / 8 + 255) / 256), 256, 0, stream>>>(entity_w, e8);

        // --- layer 0 (f32 precision) ---
        sel_init_kernel<<<(NSEL * EMBED) / 256, 256, 0, stream>>>(
            entity_w, users, items, neg_items, sel);

        // --- layer 1: full ---
        spmm_h_kernel<0><<<4096, 256, 0, stream>>>(e8, h1, rowptr, epack, nullptr, nullptr);
        sel_add_fp8_kernel<<<(NSEL * 32) / 256, 256, 0, stream>>>(
            h1, users, items, neg_items, sel);

        // --- layer 2: compacted needed-row list ---
        spmm_h_kernel<1><<<4096, 256, 0, stream>>>(h1, h2, rowptr, epack, rowlist, nrow);
        sel_add_fp8_kernel<<<(NSEL * 32) / 256, 256, 0, stream>>>(
            h2, users, items, neg_items, sel);

        // --- layer 3: direct pull into sel ---
        sel_pull_kernel<<<(NSEL + 3) / 4, 256, 0, stream>>>(
            h2, users, items, neg_items, rowptr, epack, sel);

        loss_kernel<<<BATCH, 64, 0, stream>>>(sel, qenc, out);
    } else {
        // -------- fallback: atomic path (~105 MB ws) --------
        float* hA   = (float*)d_ws;
        float* hB   = hA + HN;
        float* sel  = hB + HN;
        float* qenc = sel + (size_t)NSEL * EMBED;
        unsigned int* bm = (unsigned int*)(qenc + (size_t)BATCH * EMBED);

        hipMemsetAsync(bm, 0, sizeof(unsigned int) * BM_WORDS, stream);
        bitmap_build_kernel<<<(NSEL + 255) / 256, 256, 0, stream>>>(users, items, neg_items, bm);
        sel_accum_kernel<<<(NSEL * EMBED) / 256, 256, 0, stream>>>(
            entity_w, users, items, neg_items, sel, 1);
        hipMemsetAsync(hA, 0, HN * sizeof(float), stream);
        spmm_kernel<<<2048, 256, 0, stream>>>(entity_w, hA, edge_row, edge_col, edge_val, N_EDGES);
        sel_accum_kernel<<<(NSEL * EMBED) / 256, 256, 0, stream>>>(
            hA, users, items, neg_items, sel, 0);
        hipMemsetAsync(hB, 0, HN * sizeof(float), stream);
        spmm_kernel<<<2048, 256, 0, stream>>>(hA, hB, edge_row, edge_col, edge_val, N_EDGES);
        sel_accum_kernel<<<(NSEL * EMBED) / 256, 256, 0, stream>>>(
            hB, users, items, neg_items, sel, 0);
        hipMemsetAsync(hA, 0, HN * sizeof(float), stream);
        spmm_filtered_kernel<<<2048, 256, 0, stream>>>(hB, hA, edge_row, edge_col, edge_val, bm, N_EDGES);
        sel_accum_kernel<<<(NSEL * EMBED) / 256, 256, 0, stream>>>(
            hA, users, items, neg_items, sel, 0);
        sent_kernel<<<BATCH, 128, 0, stream>>>(qwords, word_w, in_proj_w, in_proj_b,
                                               out_proj_w, out_proj_b, qenc);
        loss_kernel<<<BATCH, 64, 0, stream>>>(sel, qenc, out);
    }
}

// Round 16
// 459.052 us; speedup vs baseline: 1.0315x; 1.0315x over previous
//
#include <hip/hip_runtime.h>
#include <math.h>

#define N_ENTITY 200000
#define EMBED    64
#define N_EDGES  6400000
#define BATCH    1024
#define QLEN     20
#define NNEG     5
#define NSEL     (BATCH + BATCH + BATCH*NNEG)   // 7168 gathered rows
#define BM_WORDS ((N_ENTITY + 31) / 32)
#define COLMASK  0x3FFFF
#define VALMASK  0xFFFC0000u
#define FP8SCALE 256.0f
#define FP8INV   (1.0f/256.0f)

#define BROWS     512                                // rows per bucket
#define ROWSH     9
#define NBUCKET   ((N_ENTITY + BROWS - 1) / BROWS)   // 391
#define NBLK_PART 512
#define TPART     1024                               // threads/block for hist+scatter

typedef unsigned int   uint32;
typedef unsigned short ushort16;
typedef unsigned char  uchar8;
typedef float v2f __attribute__((ext_vector_type(2)));

__device__ __forceinline__ ushort16 f2bf(float f) {
    uint32 b = __float_as_uint(f);
    uint32 r = (b + 0x7FFFu + ((b >> 16) & 1u)) >> 16;   // RNE
    return (ushort16)r;
}
__device__ __forceinline__ float pval(uint32 p) { return __uint_as_float(p & VALMASK); }
__device__ __forceinline__ v2f dec8(uint32 us) {
    return __builtin_amdgcn_cvt_pk_f32_fp8((int)us, false);
}

// ---------------------------------------------- sel helpers ---------------
__device__ __forceinline__ int sel_row(int i, const int* users, const int* items,
                                       const int* negs) {
    if (i < BATCH)        return users[i];
    if (i < 2 * BATCH)    return items[i - BATCH];
    return negs[i - 2 * BATCH];
}

// ------------------------------------------------------ edge partition ----
__global__ void part_hist_kernel(const int* __restrict__ erow,
                                 int* __restrict__ bucket_cnt,
                                 int* __restrict__ blockBase) {
    __shared__ int h[NBUCKET];
    int blk = blockIdx.x, t = threadIdx.x;
    for (int i = t; i < NBUCKET; i += TPART) h[i] = 0;
    __syncthreads();
    int per = (N_EDGES + NBLK_PART - 1) / NBLK_PART;
    int s = blk * per, e = min(s + per, N_EDGES);
    for (int j = s + t; j < e; j += TPART)
        atomicAdd(&h[erow[j] >> ROWSH], 1);
    __syncthreads();
    for (int i = t; i < NBUCKET; i += TPART)
        blockBase[blk * NBUCKET + i] = atomicAdd(&bucket_cnt[i], h[i]);
}

__global__ void bucket_scan_kernel(const int* __restrict__ cnt,
                                   int* __restrict__ bstart) {
    __shared__ int s[256];
    int t = threadIdx.x;
    int i0 = t * 2, i1 = t * 2 + 1;
    int c0 = (i0 < NBUCKET) ? cnt[i0] : 0;
    int c1 = (i1 < NBUCKET) ? cnt[i1] : 0;
    s[t] = c0 + c1; __syncthreads();
    for (int off = 1; off < 256; off <<= 1) {
        int x = (t >= off) ? s[t - off] : 0;
        __syncthreads();
        s[t] += x;
        __syncthreads();
    }
    int excl = t ? s[t - 1] : 0;
    if (i0 <= NBUCKET) { if (i0 < NBUCKET) bstart[i0] = excl; else bstart[NBUCKET] = excl; }
    excl += c0;
    if (i1 <= NBUCKET) { if (i1 < NBUCKET) bstart[i1] = excl; else bstart[NBUCKET] = excl; }
    if (t == 255) bstart[NBUCKET] = s[255];   // = N_EDGES
}

// scatter into bucket-grouped combined int2 stream (single stream, 8 B/edge)
__global__ void part_scatter_kernel(const int* __restrict__ erow,
                                    const int* __restrict__ ecol,
                                    const float* __restrict__ evalv,
                                    const int* __restrict__ bstart,
                                    const int* __restrict__ blockBase,
                                    int2* __restrict__ ebuf) {
    __shared__ int cur[NBUCKET];
    int blk = blockIdx.x, t = threadIdx.x;
    for (int i = t; i < NBUCKET; i += TPART)
        cur[i] = bstart[i] + blockBase[blk * NBUCKET + i];
    __syncthreads();
    int per = (N_EDGES + NBLK_PART - 1) / NBLK_PART;
    int s = blk * per, e = min(s + per, N_EDGES);
    int j = s + t;
    for (; j + TPART < e; j += 2 * TPART) {
        int   r0 = erow[j],       r1 = erow[j + TPART];
        int   c0 = ecol[j],       c1 = ecol[j + TPART];
        float v0 = evalv[j],      v1 = evalv[j + TPART];
        int p0 = atomicAdd(&cur[r0 >> ROWSH], 1);
        int p1 = atomicAdd(&cur[r1 >> ROWSH], 1);
        ebuf[p0] = make_int2(c0 | ((r0 & (BROWS-1)) << 18), (int)f2bf(v0));
        ebuf[p1] = make_int2(c1 | ((r1 & (BROWS-1)) << 18), (int)f2bf(v1));
    }
    for (; j < e; j += TPART) {
        int   r = erow[j];
        int   c = ecol[j];
        float v = evalv[j];
        int pos = atomicAdd(&cur[r >> ROWSH], 1);
        ebuf[pos] = make_int2(c | ((r & (BROWS-1)) << 18), (int)f2bf(v));
    }
}

// ----------------- bucket-local counting sort -> exact CSR (packed 4B) ----
__global__ void bucket_sort_kernel(const int2* __restrict__ ebuf,
                                   const int* __restrict__ bstart,
                                   int* __restrict__ epack,
                                   int* __restrict__ rowptr) {
    __shared__ int cur[BROWS];
    int b = blockIdx.x, t = threadIdx.x;   // t in [0,512)
    int beg = bstart[b], end = bstart[b + 1];
    cur[t] = 0;
    __syncthreads();
    for (int j = beg + t; j < end; j += BROWS)
        atomicAdd(&cur[((unsigned)ebuf[j].x) >> 18], 1);
    __syncthreads();
    int own = cur[t];
    __syncthreads();
    cur[t] = own;
    __syncthreads();
    for (int off = 1; off < BROWS; off <<= 1) {
        int x = (t >= off) ? cur[t - off] : 0;
        __syncthreads();
        cur[t] += x;
        __syncthreads();
    }
    int excl = cur[t] - own;
    __syncthreads();
    int r = (b << ROWSH) + t;
    if (r <= N_ENTITY) rowptr[r] = beg + excl;
    cur[t] = beg + excl;
    __syncthreads();
    for (int j = beg + t; j < end; j += BROWS) {
        int2 e = ebuf[j];
        int pos = atomicAdd(&cur[((unsigned)e.x) >> 18], 1);   // LDS atomic
        // pack: col[17:0] | bf16val[15:2]<<18  (val = top 14 bits of bf16)
        epack[pos] = (e.x & COLMASK) | ((e.y & 0xFFFC) << 16);
    }
}

// ---------------------- needed-rows bitmap (sel rows + their neighbors) ---
__global__ void need_build_kernel(const int* __restrict__ users,
                                  const int* __restrict__ items,
                                  const int* __restrict__ negs,
                                  const int* __restrict__ rowptr,
                                  const int* __restrict__ epack,
                                  unsigned int* __restrict__ bm) {
    int lane = threadIdx.x & 63;
    int wave = blockIdx.x * (blockDim.x >> 6) + (threadIdx.x >> 6);
    if (wave >= NSEL) return;
    int idx = sel_row(wave, users, items, negs);
    if (lane == 0) atomicOr(&bm[idx >> 5], 1u << (idx & 31));
    int beg = rowptr[idx], end = rowptr[idx + 1];
    for (int j = beg + lane; j < end; j += 64) {
        int c = epack[j] & COLMASK;
        atomicOr(&bm[c >> 5], 1u << (c & 31));
    }
}

// ------------------------- expand bmNeed into an (unordered) row list -----
__global__ void list_build_kernel(const unsigned int* __restrict__ bm,
                                  int* __restrict__ rowlist,
                                  int* __restrict__ nrow) {
    int w = blockIdx.x * blockDim.x + threadIdx.x;
    if (w >= BM_WORDS) return;
    unsigned int m = bm[w];
    if (!m) return;
    int n = __popc(m);
    int base = atomicAdd(nrow, n);
    while (m) {
        int b = __ffs(m) - 1;
        m &= m - 1;
        rowlist[base++] = (w << 5) + b;
    }
}

// ------------------------------------ entity -> fp8 (scaled x256) --------
__global__ void conv_fp8_kernel(const float* __restrict__ src,
                                uchar8* __restrict__ dst) {
    int i = (blockIdx.x * blockDim.x + threadIdx.x) * 8;
    if (i >= N_ENTITY * EMBED) return;
    float4 v0 = *(const float4*)&src[i];
    float4 v1 = *(const float4*)&src[i + 4];
    int w0 = __builtin_amdgcn_cvt_pk_fp8_f32(v0.x * FP8SCALE, v0.y * FP8SCALE, 0, false);
    w0     = __builtin_amdgcn_cvt_pk_fp8_f32(v0.z * FP8SCALE, v0.w * FP8SCALE, w0, true);
    int w1 = __builtin_amdgcn_cvt_pk_fp8_f32(v1.x * FP8SCALE, v1.y * FP8SCALE, 0, false);
    w1     = __builtin_amdgcn_cvt_pk_fp8_f32(v1.z * FP8SCALE, v1.w * FP8SCALE, w1, true);
    *(uint2*)&dst[i] = make_uint2((uint32)w0, (uint32)w1);
}

// ------------------------------- half-wave fp8 CSR SpMM (packed edges) ----
template<int USELIST>
__global__ void spmm_h_kernel(const uchar8* __restrict__ src,
                              uchar8* __restrict__ dst,
                              const int* __restrict__ rowptr,
                              const int* __restrict__ epack,
                              const int* __restrict__ rowlist,
                              const int* __restrict__ nrowp) {
    int lane = threadIdx.x & 63;
    int half = lane >> 5;
    int l2   = lane & 31;
    int wave  = blockIdx.x * (blockDim.x >> 6) + (threadIdx.x >> 6);
    int nwave = gridDim.x * (blockDim.x >> 6);
    int nrow = USELIST ? *nrowp : N_ENTITY;
    for (int it = wave; it < nrow; it += nwave) {
        int row = USELIST ? rowlist[it] : it;
        int beg = rowptr[row], end = rowptr[row + 1];
        int cnt = end - beg;
        int h0  = cnt - (cnt >> 1);               // ceil half for half 0
        int s   = beg + half * h0;
        int e   = half ? end : (beg + h0);
        float ax = 0.f, ay = 0.f;
        int j = s;
        for (; j + 7 < e; j += 8) {
            int4 ca = *(const int4*)&epack[j];
            int4 cb = *(const int4*)&epack[j + 4];
            ushort16 u0 = *(const ushort16*)(src + (size_t)(ca.x & COLMASK) * EMBED + l2 * 2);
            ushort16 u1 = *(const ushort16*)(src + (size_t)(ca.y & COLMASK) * EMBED + l2 * 2);
            ushort16 u2 = *(const ushort16*)(src + (size_t)(ca.z & COLMASK) * EMBED + l2 * 2);
            ushort16 u3 = *(const ushort16*)(src + (size_t)(ca.w & COLMASK) * EMBED + l2 * 2);
            ushort16 u4 = *(const ushort16*)(src + (size_t)(cb.x & COLMASK) * EMBED + l2 * 2);
            ushort16 u5 = *(const ushort16*)(src + (size_t)(cb.y & COLMASK) * EMBED + l2 * 2);
            ushort16 u6 = *(const ushort16*)(src + (size_t)(cb.z & COLMASK) * EMBED + l2 * 2);
            ushort16 u7 = *(const ushort16*)(src + (size_t)(cb.w & COLMASK) * EMBED + l2 * 2);
            float v0 = pval(ca.x), v1 = pval(ca.y), v2 = pval(ca.z), v3 = pval(ca.w);
            float v4 = pval(cb.x), v5 = pval(cb.y), v6 = pval(cb.z), v7 = pval(cb.w);
            v2f x0 = dec8(u0), x1 = dec8(u1), x2 = dec8(u2), x3 = dec8(u3);
            v2f x4 = dec8(u4), x5 = dec8(u5), x6 = dec8(u6), x7 = dec8(u7);
            ax += v0 * x0.x;  ay += v0 * x0.y;
            ax += v1 * x1.x;  ay += v1 * x1.y;
            ax += v2 * x2.x;  ay += v2 * x2.y;
            ax += v3 * x3.x;  ay += v3 * x3.y;
            ax += v4 * x4.x;  ay += v4 * x4.y;
            ax += v5 * x5.x;  ay += v5 * x5.y;
            ax += v6 * x6.x;  ay += v6 * x6.y;
            ax += v7 * x7.x;  ay += v7 * x7.y;
        }
        for (; j + 3 < e; j += 4) {
            int4 ca = *(const int4*)&epack[j];
            ushort16 u0 = *(const ushort16*)(src + (size_t)(ca.x & COLMASK) * EMBED + l2 * 2);
            ushort16 u1 = *(const ushort16*)(src + (size_t)(ca.y & COLMASK) * EMBED + l2 * 2);
            ushort16 u2 = *(const ushort16*)(src + (size_t)(ca.z & COLMASK) * EMBED + l2 * 2);
            ushort16 u3 = *(const ushort16*)(src + (size_t)(ca.w & COLMASK) * EMBED + l2 * 2);
            float v0 = pval(ca.x), v1 = pval(ca.y), v2 = pval(ca.z), v3 = pval(ca.w);
            v2f x0 = dec8(u0), x1 = dec8(u1), x2 = dec8(u2), x3 = dec8(u3);
            ax += v0 * x0.x;  ay += v0 * x0.y;
            ax += v1 * x1.x;  ay += v1 * x1.y;
            ax += v2 * x2.x;  ay += v2 * x2.y;
            ax += v3 * x3.x;  ay += v3 * x3.y;
        }
        for (; j < e; ++j) {
            uint32 pe = (uint32)epack[j];
            ushort16 u = *(const ushort16*)(src + (size_t)(pe & COLMASK) * EMBED + l2 * 2);
            float v = pval(pe);
            v2f x = dec8(u);
            ax += v * x.x;
            ay += v * x.y;
        }
        ax += __shfl_xor(ax, 32);
        ay += __shfl_xor(ay, 32);
        if (half == 0) {
            int pk = __builtin_amdgcn_cvt_pk_fp8_f32(ax, ay, 0, false);
            *(ushort16*)(dst + (size_t)row * EMBED + l2 * 2) = (ushort16)pk;
        }
    }
}

// layer-3 direct pull: sel[i] += (1/S) * sum_j val * h2[col]   (h2 fp8 xS)
__global__ void sel_pull_kernel(const uchar8* __restrict__ h,
                                const int* __restrict__ users,
                                const int* __restrict__ items,
                                const int* __restrict__ negs,
                                const int* __restrict__ rowptr,
                                const int* __restrict__ epack,
                                float* __restrict__ sel) {
    int lane = threadIdx.x & 63;
    int half = lane >> 5;
    int l2   = lane & 31;
    int wave = blockIdx.x * (blockDim.x >> 6) + (threadIdx.x >> 6);
    if (wave >= NSEL) return;
    int idx = sel_row(wave, users, items, negs);
    int beg = rowptr[idx], end = rowptr[idx + 1];
    int cnt = end - beg;
    int h0  = cnt - (cnt >> 1);
    int s   = beg + half * h0;
    int e   = half ? end : (beg + h0);
    float ax = 0.f, ay = 0.f;
    int j = s;
    for (; j + 7 < e; j += 8) {
        int4 ca = *(const int4*)&epack[j];
        int4 cb = *(const int4*)&epack[j + 4];
        ushort16 u0 = *(const ushort16*)(h + (size_t)(ca.x & COLMASK) * EMBED + l2 * 2);
        ushort16 u1 = *(const ushort16*)(h + (size_t)(ca.y & COLMASK) * EMBED + l2 * 2);
        ushort16 u2 = *(const ushort16*)(h + (size_t)(ca.z & COLMASK) * EMBED + l2 * 2);
        ushort16 u3 = *(const ushort16*)(h + (size_t)(ca.w & COLMASK) * EMBED + l2 * 2);
        ushort16 u4 = *(const ushort16*)(h + (size_t)(cb.x & COLMASK) * EMBED + l2 * 2);
        ushort16 u5 = *(const ushort16*)(h + (size_t)(cb.y & COLMASK) * EMBED + l2 * 2);
        ushort16 u6 = *(const ushort16*)(h + (size_t)(cb.z & COLMASK) * EMBED + l2 * 2);
        ushort16 u7 = *(const ushort16*)(h + (size_t)(cb.w & COLMASK) * EMBED + l2 * 2);
        float v0 = pval(ca.x), v1 = pval(ca.y), v2 = pval(ca.z), v3 = pval(ca.w);
        float v4 = pval(cb.x), v5 = pval(cb.y), v6 = pval(cb.z), v7 = pval(cb.w);
        v2f x0 = dec8(u0), x1 = dec8(u1), x2 = dec8(u2), x3 = dec8(u3);
        v2f x4 = dec8(u4), x5 = dec8(u5), x6 = dec8(u6), x7 = dec8(u7);
        ax += v0 * x0.x;  ay += v0 * x0.y;
        ax += v1 * x1.x;  ay += v1 * x1.y;
        ax += v2 * x2.x;  ay += v2 * x2.y;
        ax += v3 * x3.x;  ay += v3 * x3.y;
        ax += v4 * x4.x;  ay += v4 * x4.y;
        ax += v5 * x5.x;  ay += v5 * x5.y;
        ax += v6 * x6.x;  ay += v6 * x6.y;
        ax += v7 * x7.x;  ay += v7 * x7.y;
    }
    for (; j < e; ++j) {
        uint32 pe = (uint32)epack[j];
        ushort16 u = *(const ushort16*)(h + (size_t)(pe & COLMASK) * EMBED + l2 * 2);
        float v = pval(pe);
        v2f x = dec8(u);
        ax += v * x.x;
        ay += v * x.y;
    }
    ax += __shfl_xor(ax, 32);
    ay += __shfl_xor(ay, 32);
    if (half == 0) {
        sel[(size_t)wave * EMBED + l2 * 2]     += ax * FP8INV;
        sel[(size_t)wave * EMBED + l2 * 2 + 1] += ay * FP8INV;
    }
}

// ------------------------------------------------- sel accumulate ---------
__global__ void sel_init_kernel(const float* __restrict__ h,
                                const int* __restrict__ users,
                                const int* __restrict__ items,
                                const int* __restrict__ negs,
                                float* __restrict__ sel) {
    int tid = blockIdx.x * blockDim.x + threadIdx.x;
    if (tid >= NSEL * EMBED) return;
    int i = tid >> 6, d = tid & 63;
    int idx = sel_row(i, users, items, negs);
    sel[tid] = h[(size_t)idx * EMBED + d];
}

__global__ void sel_add_fp8_kernel(const uchar8* __restrict__ h,
                                   const int* __restrict__ users,
                                   const int* __restrict__ items,
                                   const int* __restrict__ negs,
                                   float* __restrict__ sel) {
    int tid = blockIdx.x * blockDim.x + threadIdx.x;
    if (tid >= NSEL * 32) return;
    int i = tid >> 5, d2 = tid & 31;
    int idx = sel_row(i, users, items, negs);
    ushort16 u = *(const ushort16*)(h + (size_t)idx * EMBED + d2 * 2);
    v2f x = dec8(u);
    sel[(size_t)i * EMBED + d2 * 2]     += x.x * FP8INV;
    sel[(size_t)i * EMBED + d2 * 2 + 1] += x.y * FP8INV;
}

// ------------------------------------ sentence encode: qkv projection -----
__global__ void qkv_kernel(const int* __restrict__ qwords,
                           const float* __restrict__ word_w,
                           const float* __restrict__ Win,
                           const float* __restrict__ bin,
                           float* __restrict__ qkv_g) {
    __shared__ float Wl[192][65];
    __shared__ float xw[QLEN][65];
    __shared__ float bl[192];
    int b = blockIdx.x, t = threadIdx.x;   // 256 threads

    for (int j = t; j < 192 * EMBED; j += 256) {
        int o = j >> 6, d = j & 63;
        Wl[o][d] = Win[j];
    }
    for (int j = t; j < 192; j += 256) bl[j] = bin[j];
    for (int j = t; j < QLEN * EMBED; j += 256) {
        int q = j >> 6, d = j & 63;
        int w = qwords[b * QLEN + q];
        xw[q][d] = word_w[(size_t)w * EMBED + d];
    }
    __syncthreads();

    for (int j = t; j < QLEN * 192; j += 256) {
        int q = j / 192, o = j % 192;
        float acc = bl[o];
        #pragma unroll
        for (int d = 0; d < EMBED; ++d) acc += xw[q][d] * Wl[o][d];
        qkv_g[(size_t)b * QLEN * 192 + j] = acc;
    }
}

// ------------------------------------- sentence encode: attention + out ---
__global__ void attn_kernel(const float* __restrict__ qkv_g,
                            const float* __restrict__ Wout,
                            const float* __restrict__ bout,
                            float* __restrict__ qenc) {
    __shared__ float qs[QLEN][195];
    __shared__ float ctx[QLEN][68];
    __shared__ float Wl[64][65];
    __shared__ float mctx[EMBED];
    int b = blockIdx.x, t = threadIdx.x;   // 128 threads

    for (int j = t; j < QLEN * 192; j += 128) {
        int q = j / 192, o = j % 192;
        qs[q][o] = qkv_g[(size_t)b * QLEN * 192 + j];
    }
    for (int j = t; j < EMBED * EMBED; j += 128) {
        int o = j >> 6, d = j & 63;
        Wl[o][d] = Wout[j];
    }
    __syncthreads();

    if (t < 4 * QLEN) {
        int h = t / QLEN, i = t % QLEN;
        float sc[QLEN];
        float mx = -1e30f;
        #pragma unroll
        for (int k = 0; k < QLEN; ++k) {
            float s = 0.f;
            #pragma unroll
            for (int d = 0; d < 16; ++d)
                s += qs[i][h*16 + d] * qs[k][EMBED + h*16 + d];
            s *= 0.25f;
            sc[k] = s;
            mx = fmaxf(mx, s);
        }
        float denom = 0.f;
        #pragma unroll
        for (int k = 0; k < QLEN; ++k) { sc[k] = expf(sc[k] - mx); denom += sc[k]; }
        float inv = 1.0f / denom;
        #pragma unroll
        for (int d = 0; d < 16; ++d) {
            float acc = 0.f;
            #pragma unroll
            for (int k = 0; k < QLEN; ++k)
                acc += sc[k] * qs[k][2*EMBED + h*16 + d];
            ctx[i][h*16 + d] = acc * inv;
        }
    }
    __syncthreads();

    if (t < EMBED) {
        float acc = 0.f;
        #pragma unroll
        for (int q = 0; q < QLEN; ++q) acc += ctx[q][t];
        mctx[t] = acc * (1.0f / QLEN);
    }
    __syncthreads();

    if (t < EMBED) {
        float acc = bout[t];
        #pragma unroll
        for (int d = 0; d < EMBED; ++d) acc += mctx[d] * Wl[t][d];
        qenc[b * EMBED + t] = acc;
    }
}

// --------------------------------------- fallback (atomic) path -----------
__global__ void spmm_kernel(const float* __restrict__ src, float* __restrict__ dst,
                            const int* __restrict__ erow, const int* __restrict__ ecol,
                            const float* __restrict__ evalv, int n_edges) {
    int lane  = threadIdx.x & 63;
    int wave  = blockIdx.x * (blockDim.x >> 6) + (threadIdx.x >> 6);
    int nwave = gridDim.x * (blockDim.x >> 6);
    for (int e = wave; e < n_edges; e += nwave) {
        int   r = erow[e];
        int   c = ecol[e];
        float v = evalv[e];
        float x = src[(size_t)c * EMBED + lane];
        atomicAdd(&dst[(size_t)r * EMBED + lane], v * x);
    }
}

__global__ void spmm_filtered_kernel(const float* __restrict__ src, float* __restrict__ dst,
                                     const int* __restrict__ erow, const int* __restrict__ ecol,
                                     const float* __restrict__ evalv,
                                     const unsigned int* __restrict__ bm, int n_edges) {
    int lane  = threadIdx.x & 63;
    int wave  = blockIdx.x * (blockDim.x >> 6) + (threadIdx.x >> 6);
    int nwave = gridDim.x * (blockDim.x >> 6);
    for (int e = wave; e < n_edges; e += nwave) {
        int r = erow[e];
        if (!((bm[r >> 5] >> (r & 31)) & 1u)) continue;
        int   c = ecol[e];
        float v = evalv[e];
        float x = src[(size_t)c * EMBED + lane];
        atomicAdd(&dst[(size_t)r * EMBED + lane], v * x);
    }
}

__global__ void bitmap_build_kernel(const int* __restrict__ users,
                                    const int* __restrict__ items,
                                    const int* __restrict__ negs,
                                    unsigned int* __restrict__ bm) {
    int i = blockIdx.x * blockDim.x + threadIdx.x;
    if (i >= NSEL) return;
    int idx = sel_row(i, users, items, negs);
    atomicOr(&bm[idx >> 5], 1u << (idx & 31));
}

__global__ void sel_accum_kernel(const float* __restrict__ h,
                                 const int* __restrict__ users,
                                 const int* __restrict__ items,
                                 const int* __restrict__ negs,
                                 float* __restrict__ sel, int init) {
    int tid = blockIdx.x * blockDim.x + threadIdx.x;
    if (tid >= NSEL * EMBED) return;
    int i = tid >> 6, d = tid & 63;
    int idx = sel_row(i, users, items, negs);
    float v = h[(size_t)idx * EMBED + d];
    if (init) sel[tid] = v;
    else      sel[tid] += v;
}

__global__ void sent_kernel(const int* __restrict__ qwords,
                            const float* __restrict__ word_w,
                            const float* __restrict__ Win,  const float* __restrict__ bin,
                            const float* __restrict__ Wout, const float* __restrict__ bout,
                            float* __restrict__ qenc) {
    __shared__ float x[QLEN][EMBED];
    __shared__ float qkv[QLEN][3*EMBED];
    __shared__ float ctx[QLEN][EMBED];
    __shared__ float mctx[EMBED];
    int b = blockIdx.x;
    int t = threadIdx.x;   // 0..127

    for (int j = t; j < QLEN*EMBED; j += 128) {
        int q = j >> 6, d = j & 63;
        int w = qwords[b*QLEN + q];
        x[q][d] = word_w[(size_t)w * EMBED + d];
    }
    __syncthreads();
    for (int j = t; j < QLEN*192; j += 128) {
        int q = j / 192, o = j % 192;
        float acc = bin[o];
        const float* wrow = &Win[o*EMBED];
        #pragma unroll
        for (int d = 0; d < EMBED; ++d) acc += x[q][d] * wrow[d];
        qkv[q][o] = acc;
    }
    __syncthreads();
    if (t < 4*QLEN) {
        int h = t / QLEN, i = t % QLEN;
        float sc[QLEN];
        float mx = -1e30f;
        #pragma unroll
        for (int k = 0; k < QLEN; ++k) {
            float s = 0.f;
            #pragma unroll
            for (int d = 0; d < 16; ++d)
                s += qkv[i][h*16 + d] * qkv[k][EMBED + h*16 + d];
            s *= 0.25f;
            sc[k] = s;
            mx = fmaxf(mx, s);
        }
        float denom = 0.f;
        #pragma unroll
        for (int k = 0; k < QLEN; ++k) { sc[k] = expf(sc[k] - mx); denom += sc[k]; }
        float inv = 1.0f / denom;
        #pragma unroll
        for (int d = 0; d < 16; ++d) {
            float acc = 0.f;
            #pragma unroll
            for (int k = 0; k < QLEN; ++k)
                acc += sc[k] * qkv[k][2*EMBED + h*16 + d];
            ctx[i][h*16 + d] = acc * inv;
        }
    }
    __syncthreads();
    if (t < EMBED) {
        float acc = 0.f;
        #pragma unroll
        for (int q = 0; q < QLEN; ++q) acc += ctx[q][t];
        mctx[t] = acc * (1.0f/QLEN);
    }
    __syncthreads();
    if (t < EMBED) {
        float acc = bout[t];
        const float* wrow = &Wout[t*EMBED];
        #pragma unroll
        for (int d = 0; d < EMBED; ++d) acc += mctx[d] * wrow[d];
        qenc[b*EMBED + t] = acc;
    }
}

// ----------------------------------------------------------------- losses --
__device__ __forceinline__ float log_sigmoid(float x) {
    float l = log1pf(expf(-fabsf(x)));
    return x >= 0.f ? -l : x - l;
}
__device__ __forceinline__ float wred(float v) {
    #pragma unroll
    for (int off = 32; off; off >>= 1) v += __shfl_xor(v, off);
    return v;
}

__global__ void loss_kernel(const float* __restrict__ sel,
                            const float* __restrict__ qenc,
                            float* __restrict__ out) {
    int b = blockIdx.x;
    int d = threadIdx.x;   // 0..63
    const float scale = 0.25f;
    float u   = sel[(size_t)b*EMBED + d] * scale;
    float pos = sel[(size_t)(BATCH + b)*EMBED + d] * scale;
    float p   = qenc[b*EMBED + d] + 0.1f * u;

    float s_up = wred(u * pos);
    float s_pp = wred(p * pos);
    float nu[NNEG], np_[NNEG];
    #pragma unroll
    for (int n = 0; n < NNEG; ++n) {
        float ng = sel[(size_t)(2*BATCH + b*NNEG + n)*EMBED + d] * scale;
        nu[n]  = wred(u * ng);
        np_[n] = wred(p * ng);
    }
    if (d == 0) {
        float cf = 0.f, srch_neg = 0.f;
        #pragma unroll
        for (int n = 0; n < NNEG; ++n) {
            cf       += -log_sigmoid(s_up - nu[n]);
            srch_neg += -log_sigmoid(-np_[n]);
        }
        float res = cf * (1.0f/(BATCH*NNEG))
                  + (-log_sigmoid(s_pp)) * (1.0f/BATCH)
                  + srch_neg * (1.0f/(BATCH*NNEG));
        atomicAdd(out, res);
    }
}

// ---------------------------------------------------------------- launch ---
extern "C" void kernel_launch(void* const* d_in, const int* in_sizes, int n_in,
                              void* d_out, int out_size, void* d_ws, size_t ws_size,
                              hipStream_t stream) {
    const float* entity_w   = (const float*)d_in[0];
    const float* word_w     = (const float*)d_in[1];
    const float* in_proj_w  = (const float*)d_in[2];
    const float* in_proj_b  = (const float*)d_in[3];
    const float* out_proj_w = (const float*)d_in[4];
    const float* out_proj_b = (const float*)d_in[5];
    const float* edge_val   = (const float*)d_in[6];
    const int*   users      = (const int*)d_in[7];
    const int*   items      = (const int*)d_in[8];
    const int*   qwords     = (const int*)d_in[9];
    const int*   neg_items  = (const int*)d_in[10];
    const int*   edge_row   = (const int*)d_in[11];
    const int*   edge_col   = (const int*)d_in[12];
    float* out = (float*)d_out;

    const size_t HN  = (size_t)N_ENTITY * EMBED;       // 12.8M elems
    const size_t HN8 = HN;                             // fp8 bytes (12.8 MB)
    const size_t EB  = sizeof(int2) * (size_t)N_EDGES; // 51.2 MB
    const size_t QKVN = (size_t)BATCH * QLEN * 192;

    size_t need = sizeof(int) * (size_t)N_EDGES        // epack
                + EB                                   // region A (ebuf -> e8,h1,h2)
                + sizeof(float) * (size_t)NSEL * EMBED // sel
                + sizeof(float) * (size_t)BATCH * EMBED// qenc
                + sizeof(int) * (size_t)(N_ENTITY + 1) // rowptr
                + sizeof(unsigned int) * (size_t)BM_WORDS
                + sizeof(float) * QKVN                 // qkv_g (build scratch overlays)
                + sizeof(int) * (size_t)N_ENTITY       // rowlist
                + 64;                                  // nrow + slack

    hipMemsetAsync(out, 0, sizeof(float) * out_size, stream);

    if (ws_size >= need) {
        char* base = (char*)d_ws;
        int*       epack = (int*)base;
        int2*      ebuf  = (int2*)(base + sizeof(int) * (size_t)N_EDGES);  // region A
        uchar8*    e8    = (uchar8*)ebuf;                                  // alias post-sort
        uchar8*    h1    = (uchar8*)ebuf + HN8;                            // alias post-sort
        uchar8*    h2    = (uchar8*)ebuf + 2 * HN8;                        // alias post-sort
        char* p = (char*)ebuf + EB;
        float*     sel   = (float*)p;        p += sizeof(float) * (size_t)NSEL * EMBED;
        float*     qenc  = (float*)p;        p += sizeof(float) * (size_t)BATCH * EMBED;
        int*       rowptr = (int*)p;         p += sizeof(int) * (size_t)(N_ENTITY + 1);
        unsigned int* bmNeed = (unsigned int*)p;  p += sizeof(unsigned int) * (size_t)BM_WORDS;
        float*     qkv_g = (float*)p;        p += sizeof(float) * QKVN;
        int*       rowlist = (int*)p;        p += sizeof(int) * (size_t)N_ENTITY;
        int*       nrow = (int*)p;
        // build scratch overlaid on qkv_g (dead until qkv_kernel, post-sort)
        int* bucket_cnt = (int*)qkv_g;
        int* bstart     = bucket_cnt + NBUCKET;
        int* blockBase  = bstart + NBUCKET + 1;   // ~0.8 MB << 15.7 MB

        hipMemsetAsync(bucket_cnt, 0, sizeof(int) * NBUCKET, stream);
        hipMemsetAsync(bmNeed, 0, sizeof(unsigned int) * BM_WORDS, stream);
        hipMemsetAsync(nrow, 0, sizeof(int), stream);

        // --- atomic-free CSR build -> packed 4B edges ---
        part_hist_kernel<<<NBLK_PART, TPART, 0, stream>>>(edge_row, bucket_cnt, blockBase);
        bucket_scan_kernel<<<1, 256, 0, stream>>>(bucket_cnt, bstart);
        part_scatter_kernel<<<NBLK_PART, TPART, 0, stream>>>(
            edge_row, edge_col, edge_val, bstart, blockBase, ebuf);
        bucket_sort_kernel<<<NBUCKET, BROWS, 0, stream>>>(ebuf, bstart, epack, rowptr);

        need_build_kernel<<<(NSEL + 3) / 4, 256, 0, stream>>>(
            users, items, neg_items, rowptr, epack, bmNeed);
        list_build_kernel<<<(BM_WORDS + 255) / 256, 256, 0, stream>>>(
            bmNeed, rowlist, nrow);

        // sentence encoder (qkv_g overlays dead build scratch)
        qkv_kernel<<<BATCH, 256, 0, stream>>>(qwords, word_w, in_proj_w, in_proj_b, qkv_g);
        attn_kernel<<<BATCH, 128, 0, stream>>>(qkv_g, out_proj_w, out_proj_b, qenc);

        // entity -> fp8 x256 (overwrites dead ebuf region)
        conv_fp8_kernel<<<(int)((HN / 8 + 255) / 256), 256, 0, stream>>>(entity_w, e8);

        // --- layer 0 (f32 precision) ---
        sel_init_kernel<<<(NSEL * EMBED) / 256, 256, 0, stream>>>(
            entity_w, users, items, neg_items, sel);

        // --- layer 1: full ---
        spmm_h_kernel<0><<<2048, 256, 0, stream>>>(e8, h1, rowptr, epack, nullptr, nullptr);
        sel_add_fp8_kernel<<<(NSEL * 32) / 256, 256, 0, stream>>>(
            h1, users, items, neg_items, sel);

        // --- layer 2: compacted needed-row list ---
        spmm_h_kernel<1><<<2048, 256, 0, stream>>>(h1, h2, rowptr, epack, rowlist, nrow);
        sel_add_fp8_kernel<<<(NSEL * 32) / 256, 256, 0, stream>>>(
            h2, users, items, neg_items, sel);

        // --- layer 3: direct pull into sel ---
        sel_pull_kernel<<<(NSEL + 3) / 4, 256, 0, stream>>>(
            h2, users, items, neg_items, rowptr, epack, sel);

        loss_kernel<<<BATCH, 64, 0, stream>>>(sel, qenc, out);
    } else {
        // -------- fallback: atomic path (~105 MB ws) --------
        float* hA   = (float*)d_ws;
        float* hB   = hA + HN;
        float* sel  = hB + HN;
        float* qenc = sel + (size_t)NSEL * EMBED;
        unsigned int* bm = (unsigned int*)(qenc + (size_t)BATCH * EMBED);

        hipMemsetAsync(bm, 0, sizeof(unsigned int) * BM_WORDS, stream);
        bitmap_build_kernel<<<(NSEL + 255) / 256, 256, 0, stream>>>(users, items, neg_items, bm);
        sel_accum_kernel<<<(NSEL * EMBED) / 256, 256, 0, stream>>>(
            entity_w, users, items, neg_items, sel, 1);
        hipMemsetAsync(hA, 0, HN * sizeof(float), stream);
        spmm_kernel<<<2048, 256, 0, stream>>>(entity_w, hA, edge_row, edge_col, edge_val, N_EDGES);
        sel_accum_kernel<<<(NSEL * EMBED) / 256, 256, 0, stream>>>(
            hA, users, items, neg_items, sel, 0);
        hipMemsetAsync(hB, 0, HN * sizeof(float), stream);
        spmm_kernel<<<2048, 256, 0, stream>>>(hA, hB, edge_row, edge_col, edge_val, N_EDGES);
        sel_accum_kernel<<<(NSEL * EMBED) / 256, 256, 0, stream>>>(
            hB, users, items, neg_items, sel, 0);
        hipMemsetAsync(hA, 0, HN * sizeof(float), stream);
        spmm_filtered_kernel<<<2048, 256, 0, stream>>>(hB, hA, edge_row, edge_col, edge_val, bm, N_EDGES);
        sel_accum_kernel<<<(NSEL * EMBED) / 256, 256, 0, stream>>>(
            hA, users, items, neg_items, sel, 0);
        sent_kernel<<<BATCH, 128, 0, stream>>>(qwords, word_w, in_proj_w, in_proj_b,
                                               out_proj_w, out_proj_b, qenc);
        loss_kernel<<<BATCH, 64, 0, stream>>>(sel, qenc, out);
    }
}